// Round 1
// baseline (165.991 us; speedup 1.0000x reference)
//
#include <hip/hip_runtime.h>
#include <hip/hip_bf16.h>

// EdgeWeightFromDistance: out[e] = relu(relu([x[src], y[dst], dist] @ W1 + b1) @ W2 + b2)
// E = 1e6, NODE_DIM = 64, HIDDEN = 128.
// R5: counters said latency-bound (MfmaUtil 26%, VALUBusy 39%, Occ 27%, HBM 33%):
//     per-tile serial chain idx->pos->gather->MFMA (~1700 cyc exposed) vs ~500 cyc compute
//     at only 3 waves/SIMD (84 VGPR + 64 AGPR acc = ~148 regs).
//     Fix: (a) fuse W2-dot epilogue into the t-loop (acc[8] -> 1 live pair, -56 regs),
//          (b) 3-stage software pipeline: idx 2 tiles ahead; pos+frag gathers 1 tile
//              ahead (depend only on already-resolved idx); dist is VALU at consume.
//     Bit-identical accumulation order -> absmax unchanged.

constexpr int NDIM  = 64;
constexpr int HID   = 128;
constexpr int KPAD  = 136;   // bf16 elems per Wt row: 128 data + w1r + b1 + 6 zeros; 272 B

typedef __attribute__((ext_vector_type(8))) short  short8;
typedef __attribute__((ext_vector_type(4))) int    int4v;
typedef __attribute__((ext_vector_type(4))) float  floatx4;

__device__ __forceinline__ short f2bf(float f) {
    union { __hip_bfloat16 h; short s; } cv;
    cv.h = __float2bfloat16(f);
    return cv.s;
}

__device__ __forceinline__ int pack2(float a, float b) {
    union { __hip_bfloat162 h; int u; } cv;
    cv.h = __float22bfloat162_rn(float2{a, b});
    return cv.u;
}

__device__ __forceinline__ short8 make_afrag_f32(const float* rp) {
    const floatx4 f0 = *reinterpret_cast<const floatx4*>(rp);
    const floatx4 f1 = *reinterpret_cast<const floatx4*>(rp + 4);
    union { int4v i; short8 s8; } cv;
    cv.i.x = pack2(f0.x, f0.y);
    cv.i.y = pack2(f0.z, f0.w);
    cv.i.z = pack2(f1.x, f1.y);
    cv.i.w = pack2(f1.z, f1.w);
    return cv.s8;
}

// ---- streaming fp32 -> bf16 convert of x and y into workspace ----
__global__ __launch_bounds__(256) void cvt_kernel(
    const float* __restrict__ xin, const float* __restrict__ yin,
    short* __restrict__ xb, short* __restrict__ yb, int nfl)  // nfl = elems per array
{
    const int stride = gridDim.x * blockDim.x;
    const int n8 = nfl >> 3;
    for (int i = blockIdx.x * blockDim.x + threadIdx.x; i < n8; i += stride) {
        {
            const floatx4 f0 = *reinterpret_cast<const floatx4*>(xin + i * 8);
            const floatx4 f1 = *reinterpret_cast<const floatx4*>(xin + i * 8 + 4);
            union { int4v v; short8 s; } c;
            c.v.x = pack2(f0.x, f0.y); c.v.y = pack2(f0.z, f0.w);
            c.v.z = pack2(f1.x, f1.y); c.v.w = pack2(f1.z, f1.w);
            *reinterpret_cast<short8*>(xb + i * 8) = c.s;
        }
        {
            const floatx4 f0 = *reinterpret_cast<const floatx4*>(yin + i * 8);
            const floatx4 f1 = *reinterpret_cast<const floatx4*>(yin + i * 8 + 4);
            union { int4v v; short8 s; } c;
            c.v.x = pack2(f0.x, f0.y); c.v.y = pack2(f0.z, f0.w);
            c.v.z = pack2(f1.x, f1.y); c.v.w = pack2(f1.z, f1.w);
            *reinterpret_cast<short8*>(yb + i * 8) = c.s;
        }
    }
}

// ---------------- pipeline stage buffers ----------------
struct IdxB  { int s0, d0, s1, d1; };
struct PosB  { float ax0, ay0, az0, bx0, by0, bz0;
               float ax1, ay1, az1, bx1, by1, bz1; };
struct FragB { short8 fa[4]; short8 fb[4]; };

__device__ __forceinline__ void load_idx(int tile, int wave, int lm, int E,
    const int* __restrict__ srcp, const int* __restrict__ dstp, IdxB& I)
{
    const int mb = tile * 128 + wave * 32;
    int m0 = mb + lm;       if (m0 >= E) m0 = E - 1;
    int m1 = mb + 16 + lm;  if (m1 >= E) m1 = E - 1;
    I.s0 = srcp[m0]; I.d0 = dstp[m0];
    I.s1 = srcp[m1]; I.d1 = dstp[m1];
}

__device__ __forceinline__ void load_pos(const IdxB& I,
    const float* __restrict__ px, const float* __restrict__ py, PosB& P)
{
    P.ax0 = px[I.s0 * 3 + 0]; P.ay0 = px[I.s0 * 3 + 1]; P.az0 = px[I.s0 * 3 + 2];
    P.bx0 = py[I.d0 * 3 + 0]; P.by0 = py[I.d0 * 3 + 1]; P.bz0 = py[I.d0 * 3 + 2];
    P.ax1 = px[I.s1 * 3 + 0]; P.ay1 = px[I.s1 * 3 + 1]; P.az1 = px[I.s1 * 3 + 2];
    P.bx1 = py[I.d1 * 3 + 0]; P.by1 = py[I.d1 * 3 + 1]; P.bz1 = py[I.d1 * 3 + 2];
}

template <bool BF16GATHER>
__device__ __forceinline__ void load_frags(const IdxB& I,
    const float* __restrict__ x, const float* __restrict__ y,
    const short* __restrict__ xb, const short* __restrict__ yb,
    int quad, FragB& F)
{
#pragma unroll
    for (int s = 0; s < 4; ++s) {
        const int kk = s * 32 + quad * 8;
        if (BF16GATHER) {
            const short* pa = (s < 2) ? (xb + I.s0 * NDIM + kk)
                                      : (yb + I.d0 * NDIM + (kk - 64));
            const short* pb = (s < 2) ? (xb + I.s1 * NDIM + kk)
                                      : (yb + I.d1 * NDIM + (kk - 64));
            F.fa[s] = *reinterpret_cast<const short8*>(pa);
            F.fb[s] = *reinterpret_cast<const short8*>(pb);
        } else {
            F.fa[s] = make_afrag_f32((s < 2) ? (x + I.s0 * NDIM + kk)
                                             : (y + I.d0 * NDIM + (kk - 64)));
            F.fb[s] = make_afrag_f32((s < 2) ? (x + I.s1 * NDIM + kk)
                                             : (y + I.d1 * NDIM + (kk - 64)));
        }
    }
}

__device__ __forceinline__ void compute_tile(const PosB& P, const FragB& F,
    int tile, int E, const short* Wt, int lm, int quad, int wave, int sel5,
    const float* w2v, float b2s, float* __restrict__ out)
{
    const float dx0 = P.ax0 - P.bx0, dy0 = P.ay0 - P.by0, dz0 = P.az0 - P.bz0;
    const float dist0 = sqrtf(dx0 * dx0 + dy0 * dy0 + dz0 * dz0);
    const float dx1 = P.ax1 - P.bx1, dy1 = P.ay1 - P.by1, dz1 = P.az1 - P.bz1;
    const float dist1 = sqrtf(dx1 * dx1 + dy1 * dy1 + dz1 * dz1);

    // fold-step A: k=128 -> dist, k=129 -> 1.0 (quad 0 only; others zero)
    short8 fa4, fb4;
    {
        union { int4v i; short8 s8; } ca, cb;
        const int d0 = (quad == 0) ? pack2(dist0, 1.0f) : 0;
        const int d1 = (quad == 0) ? pack2(dist1, 1.0f) : 0;
        ca.i = int4v{d0, 0, 0, 0};
        cb.i = int4v{d1, 0, 0, 0};
        fa4 = ca.s8; fb4 = cb.s8;
    }

    float p0 = 0.f, p1 = 0.f, p2 = 0.f, p3 = 0.f;
    float q0 = 0.f, q1 = 0.f, q2 = 0.f, q3 = 0.f;

    // zoff guard defeats LICM across tiles (keeps B-frags re-read from LDS, regs low)
    int zoff = 0;
    asm volatile("" : "+v"(zoff));
    const short* wr  = Wt + zoff + lm * KPAD + quad * 8;
    const short* wr5 = Wt + zoff + lm * KPAD + sel5;

#pragma unroll
    for (int t = 0; t < 8; ++t) {
        const short* base = wr + t * (16 * KPAD);
        const short8 bg0 = *reinterpret_cast<const short8*>(base);
        const short8 bg1 = *reinterpret_cast<const short8*>(base + 32);
        const short8 bg2 = *reinterpret_cast<const short8*>(base + 64);
        const short8 bg3 = *reinterpret_cast<const short8*>(base + 96);
        const short8 bg4 = *reinterpret_cast<const short8*>(wr5 + t * (16 * KPAD));
        floatx4 A{0.f, 0.f, 0.f, 0.f}, B{0.f, 0.f, 0.f, 0.f};
        A = __builtin_amdgcn_mfma_f32_16x16x32_bf16(F.fa[0], bg0, A, 0, 0, 0);
        B = __builtin_amdgcn_mfma_f32_16x16x32_bf16(F.fb[0], bg0, B, 0, 0, 0);
        A = __builtin_amdgcn_mfma_f32_16x16x32_bf16(F.fa[1], bg1, A, 0, 0, 0);
        B = __builtin_amdgcn_mfma_f32_16x16x32_bf16(F.fb[1], bg1, B, 0, 0, 0);
        A = __builtin_amdgcn_mfma_f32_16x16x32_bf16(F.fa[2], bg2, A, 0, 0, 0);
        B = __builtin_amdgcn_mfma_f32_16x16x32_bf16(F.fb[2], bg2, B, 0, 0, 0);
        A = __builtin_amdgcn_mfma_f32_16x16x32_bf16(F.fa[3], bg3, A, 0, 0, 0);
        B = __builtin_amdgcn_mfma_f32_16x16x32_bf16(F.fb[3], bg3, B, 0, 0, 0);
        A = __builtin_amdgcn_mfma_f32_16x16x32_bf16(fa4,    bg4, A, 0, 0, 0);
        B = __builtin_amdgcn_mfma_f32_16x16x32_bf16(fb4,    bg4, B, 0, 0, 0);
        // fused epilogue slice: relu + dot-W2 contribution for this n-tile
        p0 += fmaxf(A[0], 0.f) * w2v[t];
        p1 += fmaxf(A[1], 0.f) * w2v[t];
        p2 += fmaxf(A[2], 0.f) * w2v[t];
        p3 += fmaxf(A[3], 0.f) * w2v[t];
        q0 += fmaxf(B[0], 0.f) * w2v[t];
        q1 += fmaxf(B[1], 0.f) * w2v[t];
        q2 += fmaxf(B[2], 0.f) * w2v[t];
        q3 += fmaxf(B[3], 0.f) * w2v[t];
    }

#pragma unroll
    for (int off = 1; off < 16; off <<= 1) {
        p0 += __shfl_xor(p0, off, 64);
        p1 += __shfl_xor(p1, off, 64);
        p2 += __shfl_xor(p2, off, 64);
        p3 += __shfl_xor(p3, off, 64);
        q0 += __shfl_xor(q0, off, 64);
        q1 += __shfl_xor(q1, off, 64);
        q2 += __shfl_xor(q2, off, 64);
        q3 += __shfl_xor(q3, off, 64);
    }
    if (lm < 4) {
        const int mb = tile * 128 + wave * 32;
        const float vA = (lm == 0) ? p0 : (lm == 1) ? p1 : (lm == 2) ? p2 : p3;
        const float vB = (lm == 0) ? q0 : (lm == 1) ? q1 : (lm == 2) ? q2 : q3;
        const int eA = mb + quad * 4 + lm;
        const int eB = mb + 16 + quad * 4 + lm;
        if (eA < E) out[eA] = fmaxf(vA + b2s, 0.f);
        if (eB < E) out[eB] = fmaxf(vB + b2s, 0.f);
    }
}

template <bool BF16GATHER>
__global__ __launch_bounds__(256, 3) void edge_mlp_kernel(
    const float* __restrict__ x, const float* __restrict__ y,
    const short* __restrict__ xb, const short* __restrict__ yb,
    const int*  __restrict__ ei, const float* __restrict__ px,
    const float* __restrict__ py, const float* __restrict__ W1,
    const float* __restrict__ b1, const float* __restrict__ W2,
    const float* __restrict__ b2, float* __restrict__ out, int E)
{
    __shared__ __align__(16) short Wt[HID * KPAD];   // W1^T [n][k] in bf16 (+ fold rows)

    const int tid = threadIdx.x;

    // ---- stage W1[0:128][0:128] transposed into LDS ----
    for (int base = 0; base < HID * HID; base += 256 * 8) {
        float f[8];
#pragma unroll
        for (int u = 0; u < 8; ++u) f[u] = W1[base + u * 256 + tid];
#pragma unroll
        for (int u = 0; u < 8; ++u) {
            int i = base + u * 256 + tid;
            Wt[(i & 127) * KPAD + (i >> 7)] = f2bf(f[u]);
        }
    }
    // fold rows: k=128 -> w1r (dist coeff), k=129 -> b1, k=130..135 -> 0
    if (tid < HID) {
        const int n = tid;
        Wt[n * KPAD + 128] = f2bf(W1[128 * HID + n]);
        Wt[n * KPAD + 129] = f2bf(b1[n]);
#pragma unroll
        for (int j = 130; j < 136; ++j) Wt[n * KPAD + j] = 0;
    }
    __syncthreads();

    const int lane = tid & 63;
    const int wave = tid >> 6;
    const int quad = lane >> 4;
    const int lm   = lane & 15;   // A-frag row m; B-frag/C-D col n (within tile)

    float w2v[8];
#pragma unroll
    for (int t = 0; t < 8; ++t) w2v[t] = W2[t * 16 + lm];
    const float b2s = b2[0];

    const int* __restrict__ srcp = ei;
    const int* __restrict__ dstp = ei + E;

    const int sel5 = (quad == 0) ? 128 : 0;   // fold-step k-offset

    const int ntiles = (E + 127) / 128;       // 128 edges per block-iter, 32 per wave
    const int step = gridDim.x;
    int tile = blockIdx.x;
    if (tile >= ntiles) return;

    // ---- 3-stage pipeline: idx 2 ahead, pos+frags 1 ahead, dist/MFMA at consume ----
    // All loads are clamp-guarded (m >= E -> E-1), so over-range prefetches are safe.
    IdxB Ia, Ib; PosB Pa, Pb; FragB Fa, Fb;
    load_idx(tile,        wave, lm, E, srcp, dstp, Ia);
    load_idx(tile + step, wave, lm, E, srcp, dstp, Ib);
    load_pos(Ia, px, py, Pa);
    load_frags<BF16GATHER>(Ia, x, y, xb, yb, quad, Fa);

#pragma unroll 1
    for (;;) {
        // half A: compute tile (buffers a); prefetch t+1 frags/pos from Ib; idx t+2 -> Ia
        load_frags<BF16GATHER>(Ib, x, y, xb, yb, quad, Fb);
        load_pos(Ib, px, py, Pb);
        load_idx(tile + 2 * step, wave, lm, E, srcp, dstp, Ia);
        compute_tile(Pa, Fa, tile, E, Wt, lm, quad, wave, sel5, w2v, b2s, out);
        tile += step;
        if (tile >= ntiles) break;

        // half B: roles swapped
        load_frags<BF16GATHER>(Ia, x, y, xb, yb, quad, Fa);
        load_pos(Ia, px, py, Pa);
        load_idx(tile + 2 * step, wave, lm, E, srcp, dstp, Ib);
        compute_tile(Pb, Fb, tile, E, Wt, lm, quad, wave, sel5, w2v, b2s, out);
        tile += step;
        if (tile >= ntiles) break;
    }
}

extern "C" void kernel_launch(void* const* d_in, const int* in_sizes, int n_in,
                              void* d_out, int out_size, void* d_ws, size_t ws_size,
                              hipStream_t stream)
{
    const float* x  = (const float*)d_in[0];
    const float* y  = (const float*)d_in[1];
    const int*   ei = (const int*)  d_in[2];
    const float* px = (const float*)d_in[3];
    const float* py = (const float*)d_in[4];
    const float* W1 = (const float*)d_in[5];
    const float* b1 = (const float*)d_in[6];
    const float* W2 = (const float*)d_in[7];
    const float* b2 = (const float*)d_in[8];
    float* out = (float*)d_out;
    const int E = in_sizes[2] / 2;
    const int nnode_elems = in_sizes[0];             // N_NODES * 64

    const size_t need = (size_t)nnode_elems * 2 * sizeof(short);
    if (ws_size >= need) {
        short* xb = (short*)d_ws;
        short* yb = xb + nnode_elems;
        cvt_kernel<<<dim3(1024), dim3(256), 0, stream>>>(x, y, xb, yb, nnode_elems);
        edge_mlp_kernel<true><<<dim3(768), dim3(256), 0, stream>>>(
            x, y, xb, yb, ei, px, py, W1, b1, W2, b2, out, E);
    } else {
        edge_mlp_kernel<false><<<dim3(768), dim3(256), 0, stream>>>(
            x, y, nullptr, nullptr, ei, px, py, W1, b1, W2, b2, out, E);
    }
}

// Round 2
// 163.313 us; speedup vs baseline: 1.0164x; 1.0164x over previous
//
#include <hip/hip_runtime.h>
#include <hip/hip_bf16.h>

// EdgeWeightFromDistance: out[e] = relu(relu([x[src], y[dst], dist] @ W1 + b1) @ W2 + b2)
// E = 1e6, NODE_DIM = 64, HIDDEN = 128.
// R6: R5 post-mortem — fused epilogue killed MFMA ILP (16 indep acc chains -> 2),
//     MfmaUtil 26->20, dur 62->79 µs. FETCH rate followed CU demand (2.7->2.2 TB/s
//     at constant 163 MB) => NOT a fetch wall; latency/occupancy-bound.
//     R6 = R4 structure (indep chains) + occupancy 3->4 waves/SIMD:
//       (a) t-loop split into 2 halves of 4, acc[4][2] (32 AGPR live, not 64),
//           sched_barrier(0) between halves so lifetimes don't re-merge;
//           8 indep 5-deep MFMA chains per half = enough ILP.
//       (b) __launch_bounds__(256,4), grid 1024 (4 blocks/CU).
//       (c) pos loads deduped: lanes 0..31 load one edge each (6 dwords),
//           dist broadcast via shfl (was 12 dwords x 64 lanes, quad-duplicated).
//     Accumulation order unchanged -> bit-identical output.

constexpr int NDIM  = 64;
constexpr int HID   = 128;
constexpr int KPAD  = 136;   // bf16 elems per Wt row: 128 data + w1r + b1 + 6 zeros; 272 B

typedef __attribute__((ext_vector_type(8))) short  short8;
typedef __attribute__((ext_vector_type(4))) int    int4v;
typedef __attribute__((ext_vector_type(4))) float  floatx4;

__device__ __forceinline__ short f2bf(float f) {
    union { __hip_bfloat16 h; short s; } cv;
    cv.h = __float2bfloat16(f);
    return cv.s;
}

__device__ __forceinline__ int pack2(float a, float b) {
    union { __hip_bfloat162 h; int u; } cv;
    cv.h = __float22bfloat162_rn(float2{a, b});
    return cv.u;
}

__device__ __forceinline__ short8 make_afrag_f32(const float* rp) {
    const floatx4 f0 = *reinterpret_cast<const floatx4*>(rp);
    const floatx4 f1 = *reinterpret_cast<const floatx4*>(rp + 4);
    union { int4v i; short8 s8; } cv;
    cv.i.x = pack2(f0.x, f0.y);
    cv.i.y = pack2(f0.z, f0.w);
    cv.i.z = pack2(f1.x, f1.y);
    cv.i.w = pack2(f1.z, f1.w);
    return cv.s8;
}

// ---- streaming fp32 -> bf16 convert of x and y into workspace ----
__global__ __launch_bounds__(256) void cvt_kernel(
    const float* __restrict__ xin, const float* __restrict__ yin,
    short* __restrict__ xb, short* __restrict__ yb, int nfl)  // nfl = elems per array
{
    const int stride = gridDim.x * blockDim.x;
    const int n8 = nfl >> 3;
    for (int i = blockIdx.x * blockDim.x + threadIdx.x; i < n8; i += stride) {
        {
            const floatx4 f0 = *reinterpret_cast<const floatx4*>(xin + i * 8);
            const floatx4 f1 = *reinterpret_cast<const floatx4*>(xin + i * 8 + 4);
            union { int4v v; short8 s; } c;
            c.v.x = pack2(f0.x, f0.y); c.v.y = pack2(f0.z, f0.w);
            c.v.z = pack2(f1.x, f1.y); c.v.w = pack2(f1.z, f1.w);
            *reinterpret_cast<short8*>(xb + i * 8) = c.s;
        }
        {
            const floatx4 f0 = *reinterpret_cast<const floatx4*>(yin + i * 8);
            const floatx4 f1 = *reinterpret_cast<const floatx4*>(yin + i * 8 + 4);
            union { int4v v; short8 s; } c;
            c.v.x = pack2(f0.x, f0.y); c.v.y = pack2(f0.z, f0.w);
            c.v.z = pack2(f1.x, f1.y); c.v.w = pack2(f1.z, f1.w);
            *reinterpret_cast<short8*>(yb + i * 8) = c.s;
        }
    }
}

template <bool BF16GATHER>
__global__ __launch_bounds__(256, 4) void edge_mlp_kernel(
    const float* __restrict__ x, const float* __restrict__ y,
    const short* __restrict__ xb, const short* __restrict__ yb,
    const int*  __restrict__ ei, const float* __restrict__ px,
    const float* __restrict__ py, const float* __restrict__ W1,
    const float* __restrict__ b1, const float* __restrict__ W2,
    const float* __restrict__ b2, float* __restrict__ out, int E)
{
    __shared__ __align__(16) short Wt[HID * KPAD];   // W1^T [n][k] in bf16 (+ fold rows)

    const int tid = threadIdx.x;

    // ---- stage W1[0:128][0:128] transposed into LDS ----
    for (int base = 0; base < HID * HID; base += 256 * 8) {
        float f[8];
#pragma unroll
        for (int u = 0; u < 8; ++u) f[u] = W1[base + u * 256 + tid];
#pragma unroll
        for (int u = 0; u < 8; ++u) {
            int i = base + u * 256 + tid;
            Wt[(i & 127) * KPAD + (i >> 7)] = f2bf(f[u]);
        }
    }
    // fold rows: k=128 -> w1r (dist coeff), k=129 -> b1, k=130..135 -> 0
    if (tid < HID) {
        const int n = tid;
        Wt[n * KPAD + 128] = f2bf(W1[128 * HID + n]);
        Wt[n * KPAD + 129] = f2bf(b1[n]);
#pragma unroll
        for (int j = 130; j < 136; ++j) Wt[n * KPAD + j] = 0;
    }
    __syncthreads();

    const int lane = tid & 63;
    const int wave = tid >> 6;
    const int quad = lane >> 4;
    const int lm   = lane & 15;   // A-frag row m; B-frag/C-D col n (within tile)

    float w2v[8];
#pragma unroll
    for (int t = 0; t < 8; ++t) w2v[t] = W2[t * 16 + lm];
    const float b2s = b2[0];

    const int* __restrict__ srcp = ei;
    const int* __restrict__ dstp = ei + E;

    const int sel5 = (quad == 0) ? 128 : 0;   // fold-step k-offset

    const int ntiles = (E + 127) / 128;       // 128 edges per block-iter, 32 per wave
    for (int tile = blockIdx.x; tile < ntiles; tile += gridDim.x) {
        const int mb = tile * 128 + wave * 32;
        int m0 = mb + lm;       if (m0 >= E) m0 = E - 1;
        int m1 = mb + 16 + lm;  if (m1 >= E) m1 = E - 1;
        const int src0 = srcp[m0], dst0 = dstp[m0];
        const int src1 = srcp[m1], dst1 = dstp[m1];

        // ---- pos + dist: lanes 0..31 each own edge mb+lane ----
        // lane<16: its m0 == mb+lane; lane 16..31: its m1 == mb+lane.
        float dd = 0.f;
        if (lane < 32) {
            const int ps = (lane < 16) ? src0 : src1;
            const int pd = (lane < 16) ? dst0 : dst1;
            const float ax = px[ps * 3 + 0] - py[pd * 3 + 0];
            const float ay = px[ps * 3 + 1] - py[pd * 3 + 1];
            const float az = px[ps * 3 + 2] - py[pd * 3 + 2];
            dd = sqrtf(ax * ax + ay * ay + az * az);
        }
        const float dist0 = __shfl(dd, lm, 64);
        const float dist1 = __shfl(dd, lm + 16, 64);

        // ---- A fragments: row m, k = s*32 + quad*8 + j ----
        short8 fa[4], fb[4];
#pragma unroll
        for (int s = 0; s < 4; ++s) {
            const int kk = s * 32 + quad * 8;
            if (BF16GATHER) {
                const short* pa = (s < 2) ? (xb + src0 * NDIM + kk)
                                          : (yb + dst0 * NDIM + (kk - 64));
                const short* pb = (s < 2) ? (xb + src1 * NDIM + kk)
                                          : (yb + dst1 * NDIM + (kk - 64));
                fa[s] = *reinterpret_cast<const short8*>(pa);
                fb[s] = *reinterpret_cast<const short8*>(pb);
            } else {
                fa[s] = make_afrag_f32((s < 2) ? (x + src0 * NDIM + kk)
                                               : (y + dst0 * NDIM + (kk - 64)));
                fb[s] = make_afrag_f32((s < 2) ? (x + src1 * NDIM + kk)
                                               : (y + dst1 * NDIM + (kk - 64)));
            }
        }
        // fold-step A: k=128 -> dist, k=129 -> 1.0 (quad 0 only; others zero)
        short8 fa4, fb4;
        {
            union { int4v i; short8 s8; } ca, cb;
            const int d0 = (quad == 0) ? pack2(dist0, 1.0f) : 0;
            const int d1 = (quad == 0) ? pack2(dist1, 1.0f) : 0;
            ca.i = int4v{d0, 0, 0, 0};
            cb.i = int4v{d1, 0, 0, 0};
            fa4 = ca.s8; fb4 = cb.s8;
        }

        float p0 = 0.f, p1 = 0.f, p2 = 0.f, p3 = 0.f;
        float q0 = 0.f, q1 = 0.f, q2 = 0.f, q3 = 0.f;

        // zoff guard defeats LICM (keeps B-frags re-read from LDS, regs low)
        int zoff = 0;
        asm volatile("" : "+v"(zoff));
        const short* wr  = Wt + zoff + lm * KPAD + quad * 8;
        const short* wr5 = Wt + zoff + lm * KPAD + sel5;

        // ---- two halves of 4 n-tiles each; acc[4][2] live per half (32 AGPR) ----
        // sched_barrier(0) between halves: lifetimes must not re-merge (occupancy).
#pragma unroll
        for (int half = 0; half < 2; ++half) {
            if (half) __builtin_amdgcn_sched_barrier(0);

            floatx4 aA[4], aB[4];
#pragma unroll
            for (int u = 0; u < 4; ++u) {
                aA[u] = floatx4{0.f, 0.f, 0.f, 0.f};
                aB[u] = floatx4{0.f, 0.f, 0.f, 0.f};
            }
#pragma unroll
            for (int u = 0; u < 4; ++u) {
                const int t = half * 4 + u;
                const short* base = wr + t * (16 * KPAD);
                const short8 bg0 = *reinterpret_cast<const short8*>(base);
                const short8 bg1 = *reinterpret_cast<const short8*>(base + 32);
                const short8 bg2 = *reinterpret_cast<const short8*>(base + 64);
                const short8 bg3 = *reinterpret_cast<const short8*>(base + 96);
                const short8 bg4 = *reinterpret_cast<const short8*>(wr5 + t * (16 * KPAD));
                aA[u] = __builtin_amdgcn_mfma_f32_16x16x32_bf16(fa[0], bg0, aA[u], 0, 0, 0);
                aB[u] = __builtin_amdgcn_mfma_f32_16x16x32_bf16(fb[0], bg0, aB[u], 0, 0, 0);
                aA[u] = __builtin_amdgcn_mfma_f32_16x16x32_bf16(fa[1], bg1, aA[u], 0, 0, 0);
                aB[u] = __builtin_amdgcn_mfma_f32_16x16x32_bf16(fb[1], bg1, aB[u], 0, 0, 0);
                aA[u] = __builtin_amdgcn_mfma_f32_16x16x32_bf16(fa[2], bg2, aA[u], 0, 0, 0);
                aB[u] = __builtin_amdgcn_mfma_f32_16x16x32_bf16(fb[2], bg2, aB[u], 0, 0, 0);
                aA[u] = __builtin_amdgcn_mfma_f32_16x16x32_bf16(fa[3], bg3, aA[u], 0, 0, 0);
                aB[u] = __builtin_amdgcn_mfma_f32_16x16x32_bf16(fb[3], bg3, aB[u], 0, 0, 0);
                aA[u] = __builtin_amdgcn_mfma_f32_16x16x32_bf16(fa4,   bg4, aA[u], 0, 0, 0);
                aB[u] = __builtin_amdgcn_mfma_f32_16x16x32_bf16(fb4,   bg4, aB[u], 0, 0, 0);
            }
            // epilogue slice for this half: relu + dot-W2 (t order preserved)
#pragma unroll
            for (int u = 0; u < 4; ++u) {
                const float w = w2v[half * 4 + u];
                p0 += fmaxf(aA[u][0], 0.f) * w;
                p1 += fmaxf(aA[u][1], 0.f) * w;
                p2 += fmaxf(aA[u][2], 0.f) * w;
                p3 += fmaxf(aA[u][3], 0.f) * w;
                q0 += fmaxf(aB[u][0], 0.f) * w;
                q1 += fmaxf(aB[u][1], 0.f) * w;
                q2 += fmaxf(aB[u][2], 0.f) * w;
                q3 += fmaxf(aB[u][3], 0.f) * w;
            }
        }

        // ---- quad-group reduce, +b2, relu, store ----
#pragma unroll
        for (int off = 1; off < 16; off <<= 1) {
            p0 += __shfl_xor(p0, off, 64);
            p1 += __shfl_xor(p1, off, 64);
            p2 += __shfl_xor(p2, off, 64);
            p3 += __shfl_xor(p3, off, 64);
            q0 += __shfl_xor(q0, off, 64);
            q1 += __shfl_xor(q1, off, 64);
            q2 += __shfl_xor(q2, off, 64);
            q3 += __shfl_xor(q3, off, 64);
        }
        if (lm < 4) {
            const float vA = (lm == 0) ? p0 : (lm == 1) ? p1 : (lm == 2) ? p2 : p3;
            const float vB = (lm == 0) ? q0 : (lm == 1) ? q1 : (lm == 2) ? q2 : q3;
            const int eA = mb + quad * 4 + lm;
            const int eB = mb + 16 + quad * 4 + lm;
            if (eA < E) out[eA] = fmaxf(vA + b2s, 0.f);
            if (eB < E) out[eB] = fmaxf(vB + b2s, 0.f);
        }
    }
}

extern "C" void kernel_launch(void* const* d_in, const int* in_sizes, int n_in,
                              void* d_out, int out_size, void* d_ws, size_t ws_size,
                              hipStream_t stream)
{
    const float* x  = (const float*)d_in[0];
    const float* y  = (const float*)d_in[1];
    const int*   ei = (const int*)  d_in[2];
    const float* px = (const float*)d_in[3];
    const float* py = (const float*)d_in[4];
    const float* W1 = (const float*)d_in[5];
    const float* b1 = (const float*)d_in[6];
    const float* W2 = (const float*)d_in[7];
    const float* b2 = (const float*)d_in[8];
    float* out = (float*)d_out;
    const int E = in_sizes[2] / 2;
    const int nnode_elems = in_sizes[0];             // N_NODES * 64

    const size_t need = (size_t)nnode_elems * 2 * sizeof(short);
    if (ws_size >= need) {
        short* xb = (short*)d_ws;
        short* yb = xb + nnode_elems;
        cvt_kernel<<<dim3(1024), dim3(256), 0, stream>>>(x, y, xb, yb, nnode_elems);
        edge_mlp_kernel<true><<<dim3(1024), dim3(256), 0, stream>>>(
            x, y, xb, yb, ei, px, py, W1, b1, W2, b2, out, E);
    } else {
        edge_mlp_kernel<false><<<dim3(1024), dim3(256), 0, stream>>>(
            x, y, nullptr, nullptr, ei, px, py, W1, b1, W2, b2, out, E);
    }
}